// Round 13
// baseline (402.273 us; speedup 1.0000x reference)
//
#include <hip/hip_runtime.h>

#define NLEV 8
#define PTS_PER_BLOCK 64
#define ROW_F 51     // 3 + 6*NLEV
#define NBIN 32768   // 32^3 Morton bins
#define SUB  16      // sub-counters per bin, STRIDED by NBIN (distinct cache lines)
#define NCNT (NBIN * SUB)

typedef unsigned int u32x4 __attribute__((ext_vector_type(4)));

// ---------------------------------------------------------------------------
// Morton bin (32^3) + deterministic sub-counter hash (same in hist & scatter)
// ---------------------------------------------------------------------------
__device__ __forceinline__ unsigned mexp5(unsigned v) {
    v = (v | (v << 8)) & 0x100Fu;
    v = (v | (v << 4)) & 0x10C3u;
    v = (v | (v << 2)) & 0x1249u;
    return v;
}
__device__ __forceinline__ unsigned point_bin(
    float x, float y, float z,
    float lox, float loy, float loz,
    float hix, float hiy, float hiz, float inv_size)
{
    const float xn = (fminf(fmaxf(x, lox), hix) - lox) * inv_size;
    const float yn = (fminf(fmaxf(y, loy), hiy) - loy) * inv_size;
    const float zn = (fminf(fmaxf(z, loz), hiz) - loz) * inv_size;
    const int bx = min(31, (int)(xn * 32.0f));
    const int by = min(31, (int)(yn * 32.0f));
    const int bz = min(31, (int)(zn * 32.0f));
    return mexp5((unsigned)bx) | (mexp5((unsigned)by) << 1) | (mexp5((unsigned)bz) << 2);
}
// line-strided counter: h*NBIN + b  (h's counters 128KB apart -> distinct lines)
__device__ __forceinline__ unsigned cnt_idx(unsigned b, int i) {
    return (((unsigned)i >> 2) & (SUB - 1)) * NBIN + b;
}

#define LOAD_BOUNDS                                                              \
    const float lox = bounds[0], loy = bounds[1], loz = bounds[2];               \
    const float hix = bounds[3] - 1e-6f;                                         \
    const float hiy = bounds[4] - 1e-6f;                                         \
    const float hiz = bounds[5] - 1e-6f;                                         \
    const float size = fmaxf(fmaxf(bounds[3] - bounds[0], bounds[4] - bounds[1]),\
                             bounds[5] - bounds[2]);                             \
    const float inv_size = 1.0f / size;

// ---------------------------------------------------------------------------
// FUSED repack16 + hist: blocks cover T anchors; first ceil(N/256) blocks also
// histogram their xyz chunk (hist pre-zeroed by memsetAsync -> no in-kernel race).
// ---------------------------------------------------------------------------
__global__ __launch_bounds__(256) void repack_hist(
    const float* __restrict__ data,
    const int*   __restrict__ level_offsets,
    const float* __restrict__ xyz,
    const float* __restrict__ bounds,
    uint4* __restrict__ tab, unsigned* __restrict__ hist, int T, int npts)
{
    __shared__ float sv[(256 + 1) * 3];
    __shared__ int   soff[NLEV];
    __shared__ float sx[256 * 3];
    const int tid  = threadIdx.x;
    const int bid  = blockIdx.x;
    const int base = bid * 256;
    const int nxb  = (npts + 255) / 256;

    if (tid < NLEV) soff[tid] = level_offsets[tid];
    for (int k = tid; k < (256 + 1) * 3; k += 256) {
        const int gi = base * 3 + k;
        sv[k] = (gi < T * 3) ? data[gi] : 0.0f;
    }
    if (bid < nxb) {
        for (int k = tid; k < 256 * 3; k += 256) {
            const int gi = base * 3 + k;
            sx[k] = (gi < npts * 3) ? xyz[gi] : 0.0f;
        }
    }
    LOAD_BOUNDS
    __syncthreads();

    // hist part
    if (bid < nxb) {
        const int i = base + tid;
        if (i < npts) {
            const unsigned b = point_bin(sx[tid*3], sx[tid*3+1], sx[tid*3+2],
                                         lox, loy, loz, hix, hiy, hiz, inv_size);
            atomicAdd(&hist[cnt_idx(b, i)], 1u);
        }
    }

    // repack part
    const int i = base + tid;
    if (i >= T) return;
    int l = 0;
    #pragma unroll
    for (int j = 1; j < NLEV; ++j) l += (i >= soff[j]) ? 1 : 0;
    const float s = (float)(1 << l) * 0.15915494309189535f;   // freq / 2pi
    unsigned q[6];
    #pragma unroll
    for (int k = 0; k < 6; ++k) {                 // k<3: anchor i, k>=3: anchor i+1
        float f = sv[tid * 3 + k] * s;
        f -= floorf(f);
        q[k] = ((unsigned)(f * 65536.0f + 0.5f)) & 0xffffu;
    }
    tab[i] = make_uint4(q[0] | (q[1] << 16), q[2], q[3] | (q[4] << 16), q[5]);
}

// ---------------------------------------------------------------------------
// scan: exclusive prefix over NCNT counters. One 1024-thread block, 512/thread.
// ---------------------------------------------------------------------------
__global__ __launch_bounds__(1024) void sort_scan(
    const unsigned* __restrict__ hist, unsigned* __restrict__ offs)
{
    __shared__ unsigned spart[1024];
    const int tid = threadIdx.x;
    const int CH  = NCNT / 1024;           // 512 counters per thread
    const int base = tid * CH;

    unsigned sum = 0;
    #pragma unroll 8
    for (int k = 0; k < CH; ++k) sum += hist[base + k];
    spart[tid] = sum;
    __syncthreads();

    for (int off = 1; off < 1024; off <<= 1) {
        const unsigned t = (tid >= off) ? spart[tid - off] : 0u;
        __syncthreads();
        spart[tid] += t;
        __syncthreads();
    }

    unsigned run = (tid > 0) ? spart[tid - 1] : 0u;   // exclusive base
    #pragma unroll 8
    for (int k = 0; k < CH; ++k) {
        const unsigned v = hist[base + k];
        offs[base + k] = run;
        run += v;
    }
}

// ---------------------------------------------------------------------------
// scatter into sorted order (indices + xyz), line-strided counter bump.
// ---------------------------------------------------------------------------
__global__ __launch_bounds__(256) void sort_scatter(
    const float* __restrict__ xyz, const float* __restrict__ bounds,
    unsigned* __restrict__ offs, int* __restrict__ g_sidx,
    float* __restrict__ g_sxyz, int npts)
{
    __shared__ float sv[256 * 3];
    const int tid = threadIdx.x;
    const int base = blockIdx.x * 256;
    for (int k = tid; k < 256 * 3; k += 256) {
        const int gi = base * 3 + k;
        sv[k] = (gi < npts * 3) ? xyz[gi] : 0.0f;
    }
    LOAD_BOUNDS
    __syncthreads();
    const int i = base + tid;
    if (i >= npts) return;
    const float x = sv[tid*3], y = sv[tid*3+1], z = sv[tid*3+2];
    const unsigned b = point_bin(x, y, z, lox, loy, loz, hix, hiy, hiz, inv_size);
    const unsigned pos = atomicAdd(&offs[cnt_idx(b, i)], 1u);
    g_sidx[pos] = i;
    g_sxyz[pos * 3 + 0] = x;
    g_sxyz[pos * 3 + 1] = y;
    g_sxyz[pos * 3 + 2] = z;
}

// sin/cos on revolutions in [0,1)
__device__ __forceinline__ void sincos_rev(float r, float& sn, float& cs) {
    asm("v_sin_f32 %0, %1" : "=v"(sn) : "v"(r));
    asm("v_cos_f32 %0, %1" : "=v"(cs) : "v"(r));
}

// ---------------------------------------------------------------------------
// Main kernel (sorted): unchanged from R11/R12 (proven 76-78 us, FETCH 40MB).
// ---------------------------------------------------------------------------
__global__ __launch_bounds__(256, 4) void dagrid_sorted(
    const float* __restrict__ g_sxyz,
    const int*   __restrict__ g_sidx,
    const uint4* __restrict__ tab,
    const float* __restrict__ scales,
    const int*   __restrict__ level_offsets,
    const float* __restrict__ bounds,
    float* __restrict__ out,
    int npts, int nwg)
{
    __shared__ alignas(16) float sxyz[PTS_PER_BLOCK * 3];
    __shared__ alignas(16) float sres[PTS_PER_BLOCK][ROW_F];
    __shared__ int sidx_l[PTS_PER_BLOCK];

    const int orig = blockIdx.x;
    const int qq = nwg >> 3, rr = nwg & 7;
    const int xcd = orig & 7, ii = orig >> 3;
    const int bid = (xcd < rr ? xcd * (qq + 1) : rr * (qq + 1) + (xcd - rr) * qq) + ii;

    const int tid = threadIdx.x;
    const int l   = tid & 7;
    const int p   = tid >> 3;
    const int block_base = bid * PTS_PER_BLOCK;
    const bool full_block = (block_base + PTS_PER_BLOCK <= npts);

    if (full_block) {
        if (tid < 48)
            ((float4*)sxyz)[tid] = ((const float4*)(g_sxyz + (size_t)block_base * 3))[tid];
    } else if (tid < PTS_PER_BLOCK * 3) {
        const int gi = block_base * 3 + tid;
        sxyz[tid] = (gi < npts * 3) ? g_sxyz[gi] : 0.0f;
    }
    if (tid < PTS_PER_BLOCK) {
        const int pos = block_base + tid;
        sidx_l[tid] = (pos < npts) ? g_sidx[pos] : -1;
    }

    const float scale = scales[l];
    const int   off_l = level_offsets[l];
    LOAD_BOUNDS
    __syncthreads();

    const float rxA = sxyz[p * 3 + 0], ryA = sxyz[p * 3 + 1], rzA = sxyz[p * 3 + 2];
    const float rxB = sxyz[(p + 32) * 3 + 0], ryB = sxyz[(p + 32) * 3 + 1],
                rzB = sxyz[(p + 32) * 3 + 2];

    const int r1   = (int)scale + 1;
    const int r1sq = r1 * r1;
    const bool actA = (block_base + p) < npts;
    const bool actB = (block_base + p + 32) < npts;

    #define ADDR(rx, ry, rz, act, ox, oy, oz, idx)                                \
    {                                                                             \
        const float x = fminf(fmaxf(rx, lox), hix);                               \
        const float y = fminf(fmaxf(ry, loy), hiy);                               \
        const float z = fminf(fmaxf(rz, loz), hiz);                               \
        const float fx = (x - lox) * inv_size * scale;                            \
        const float fy = (y - loy) * inv_size * scale;                            \
        const float fz = (z - loz) * inv_size * scale;                            \
        const float bxf = floorf(fx), byf = floorf(fy), bzf = floorf(fz);         \
        ox = fx - bxf; oy = fy - byf; oz = fz - bzf;                              \
        idx = act ? ((int)bxf * r1sq + (int)byf * r1 + (int)bzf + off_l) : 0;     \
    }
    float oxA, oyA, ozA, oxB, oyB, ozB;
    int idxA, idxB;
    ADDR(rxA, ryA, rzA, actA, oxA, oyA, ozA, idxA)
    ADDR(rxB, ryB, rzB, actB, oxB, oyB, ozB, idxB)
    #undef ADDR

    const unsigned long long baseAddr = (unsigned long long)tab;
    const unsigned long long aA = baseAddr + 16ull * (unsigned)idxA;
    const unsigned long long aB = baseAddr + 16ull * (unsigned)idxB;
    const unsigned long long sY = 16ull * (unsigned)r1;
    const unsigned long long sX = 16ull * (unsigned)r1sq;

    u32x4 eA0, eA1, eA2, eA3, eB0, eB1, eB2, eB3;
    #define GLOAD(dst, addr) \
        asm volatile("global_load_dwordx4 %0, %1, off" : "=&v"(dst) : "v"(addr))
    GLOAD(eA0, aA);
    GLOAD(eA1, aA + sY);
    GLOAD(eA2, aA + sX);
    GLOAD(eA3, aA + sX + sY);
    GLOAD(eB0, aB);
    GLOAD(eB1, aB + sY);
    GLOAD(eB2, aB + sX);
    GLOAD(eB3, aB + sX + sY);
    #undef GLOAD
    asm volatile("s_waitcnt vmcnt(0)"
                 : "+v"(eA0), "+v"(eA1), "+v"(eA2), "+v"(eA3),
                   "+v"(eB0), "+v"(eB1), "+v"(eB2), "+v"(eB3));
    __builtin_amdgcn_sched_barrier(0);

    const float K = 1.0f / 65536.0f;

    #define PAIRE(e, WXY, oz_, wz0_, a0, a1, a2, a3, a4, a5)                      \
    {                                                                             \
        const float w0 = (WXY) * (wz0_);                                          \
        const float w1 = (WXY) * (oz_);                                           \
        float sn, cs;                                                             \
        sincos_rev((float)(e.x & 0xffffu) * K, sn, cs); a0 += w0*sn; a3 += w0*cs; \
        sincos_rev((float)(e.x >> 16)     * K, sn, cs); a1 += w0*sn; a4 += w0*cs; \
        sincos_rev((float)(e.y)           * K, sn, cs); a2 += w0*sn; a5 += w0*cs; \
        sincos_rev((float)(e.z & 0xffffu) * K, sn, cs); a0 += w1*sn; a3 += w1*cs; \
        sincos_rev((float)(e.z >> 16)     * K, sn, cs); a1 += w1*sn; a4 += w1*cs; \
        sincos_rev((float)(e.w)           * K, sn, cs); a2 += w1*sn; a5 += w1*cs; \
    }

    float a0 = 0.f, a1 = 0.f, a2 = 0.f, a3 = 0.f, a4 = 0.f, a5 = 0.f;
    {
        const float wz0 = 1.0f - ozA;
        const float wx0 = 1.0f - oxA, wy0 = 1.0f - oyA;
        PAIRE(eA0, wx0 * wy0, ozA, wz0, a0, a1, a2, a3, a4, a5)
        PAIRE(eA1, wx0 * oyA, ozA, wz0, a0, a1, a2, a3, a4, a5)
        PAIRE(eA2, oxA * wy0, ozA, wz0, a0, a1, a2, a3, a4, a5)
        PAIRE(eA3, oxA * oyA, ozA, wz0, a0, a1, a2, a3, a4, a5)
    }
    float b0 = 0.f, b1 = 0.f, b2 = 0.f, b3 = 0.f, b4 = 0.f, b5 = 0.f;
    {
        const float wz0 = 1.0f - ozB;
        const float wx0 = 1.0f - oxB, wy0 = 1.0f - oyB;
        PAIRE(eB0, wx0 * wy0, ozB, wz0, b0, b1, b2, b3, b4, b5)
        PAIRE(eB1, wx0 * oyB, ozB, wz0, b0, b1, b2, b3, b4, b5)
        PAIRE(eB2, oxB * wy0, ozB, wz0, b0, b1, b2, b3, b4, b5)
        PAIRE(eB3, oxB * oyB, ozB, wz0, b0, b1, b2, b3, b4, b5)
    }
    #undef PAIRE

    {
        const int c = 3 + l * 6;
        float* rowA = sres[p];
        rowA[c + 0] = a0; rowA[c + 1] = a1; rowA[c + 2] = a2;
        rowA[c + 3] = a3; rowA[c + 4] = a4; rowA[c + 5] = a5;
        float* rowB = sres[p + 32];
        rowB[c + 0] = b0; rowB[c + 1] = b1; rowB[c + 2] = b2;
        rowB[c + 3] = b3; rowB[c + 4] = b4; rowB[c + 5] = b5;
        if (l == 0) {
            rowA[0] = rxA; rowA[1] = ryA; rowA[2] = rzA;
            rowB[0] = rxB; rowB[1] = ryB; rowB[2] = rzB;
        }
    }
    __syncthreads();

    {
        const int r = tid >> 2;        // row 0..63
        const int j = tid & 3;
        const int orig_i = sidx_l[r];
        if (orig_i >= 0) {
            float* ob = out + (size_t)orig_i * ROW_F;
            #pragma unroll
            for (int k = 0; k < 13; ++k) {
                const int ci = j + 4 * k;
                if (ci < ROW_F) ob[ci] = sres[r][ci];
            }
        }
    }
}

// ---------------------------------------------------------------------------
// Mid fallback (ws fits T*8 only): R6 known-good 8B unsorted path.
// ---------------------------------------------------------------------------
typedef unsigned int u4a8 __attribute__((ext_vector_type(4), aligned(8)));

__global__ __launch_bounds__(256) void phase_repack8(
    const float* __restrict__ data,
    const int*   __restrict__ level_offsets,
    uint2* __restrict__ tab, int T)
{
    __shared__ float sv[256 * 3];
    __shared__ int   soff[NLEV];
    const int tid  = threadIdx.x;
    const int base = blockIdx.x * 256;
    if (tid < NLEV) soff[tid] = level_offsets[tid];
    for (int k = tid; k < 256 * 3; k += 256) {
        const int gi = base * 3 + k;
        sv[k] = (gi < T * 3) ? data[gi] : 0.0f;
    }
    __syncthreads();
    const int i = base + tid;
    if (i >= T) return;
    int l = 0;
    #pragma unroll
    for (int j = 1; j < NLEV; ++j) l += (i >= soff[j]) ? 1 : 0;
    const float s = (float)(1 << l) * 0.15915494309189535f;
    unsigned q[3];
    #pragma unroll
    for (int k = 0; k < 3; ++k) {
        float f = sv[tid * 3 + k] * s;
        f -= floorf(f);
        q[k] = ((unsigned)(f * 65536.0f + 0.5f)) & 0xffffu;
    }
    tab[i] = make_uint2(q[0] | (q[1] << 16), q[2]);
}

__global__ __launch_bounds__(256, 4) void dagrid_kernel8(
    const float* __restrict__ xyz,
    const uint2* __restrict__ tab,
    const float* __restrict__ scales,
    const int*   __restrict__ level_offsets,
    const float* __restrict__ bounds,
    float* __restrict__ out,
    int npts)
{
    __shared__ alignas(16) float sxyz[PTS_PER_BLOCK * 3];
    __shared__ alignas(16) float sres[PTS_PER_BLOCK][ROW_F];

    const int tid = threadIdx.x;
    const int l   = tid & 7;
    const int p   = tid >> 3;
    const int block_base = blockIdx.x * PTS_PER_BLOCK;
    const bool full_block = (block_base + PTS_PER_BLOCK <= npts);

    if (full_block) {
        if (tid < 48)
            ((float4*)sxyz)[tid] = ((const float4*)(xyz + (size_t)block_base * 3))[tid];
    } else if (tid < PTS_PER_BLOCK * 3) {
        const int gi = block_base * 3 + tid;
        sxyz[tid] = (gi < npts * 3) ? xyz[gi] : 0.0f;
    }
    const float scale = scales[l];
    const int   off_l = level_offsets[l];
    LOAD_BOUNDS
    __syncthreads();

    const float rxA = sxyz[p * 3 + 0], ryA = sxyz[p * 3 + 1], rzA = sxyz[p * 3 + 2];
    const float rxB = sxyz[(p + 32) * 3 + 0], ryB = sxyz[(p + 32) * 3 + 1],
                rzB = sxyz[(p + 32) * 3 + 2];
    const int r1   = (int)scale + 1;
    const int r1sq = r1 * r1;
    const bool actA = (block_base + p) < npts;
    const bool actB = (block_base + p + 32) < npts;

    #define ADDR(rx, ry, rz, act, ox, oy, oz, idx)                                \
    {                                                                             \
        const float x = fminf(fmaxf(rx, lox), hix);                               \
        const float y = fminf(fmaxf(ry, loy), hiy);                               \
        const float z = fminf(fmaxf(rz, loz), hiz);                               \
        const float fx = (x - lox) * inv_size * scale;                            \
        const float fy = (y - loy) * inv_size * scale;                            \
        const float fz = (z - loz) * inv_size * scale;                            \
        const float bxf = floorf(fx), byf = floorf(fy), bzf = floorf(fz);         \
        ox = fx - bxf; oy = fy - byf; oz = fz - bzf;                              \
        idx = act ? ((int)bxf * r1sq + (int)byf * r1 + (int)bzf + off_l) : 0;     \
    }
    float oxA, oyA, ozA, oxB, oyB, ozB;
    int idxA, idxB;
    ADDR(rxA, ryA, rzA, actA, oxA, oyA, ozA, idxA)
    ADDR(rxB, ryB, rzB, actB, oxB, oyB, ozB, idxB)
    #undef ADDR

    const u4a8 eA0 = *(const u4a8*)(tab + idxA);
    const u4a8 eA1 = *(const u4a8*)(tab + idxA + r1);
    const u4a8 eA2 = *(const u4a8*)(tab + idxA + r1sq);
    const u4a8 eA3 = *(const u4a8*)(tab + idxA + r1sq + r1);
    const u4a8 eB0 = *(const u4a8*)(tab + idxB);
    const u4a8 eB1 = *(const u4a8*)(tab + idxB + r1);
    const u4a8 eB2 = *(const u4a8*)(tab + idxB + r1sq);
    const u4a8 eB3 = *(const u4a8*)(tab + idxB + r1sq + r1);

    const float K = 1.0f / 65536.0f;
    #define PAIRE(e, WXY, oz_, wz0_, a0, a1, a2, a3, a4, a5)                      \
    {                                                                             \
        const float w0 = (WXY) * (wz0_);                                          \
        const float w1 = (WXY) * (oz_);                                           \
        float sn, cs;                                                             \
        sincos_rev((float)(e.x & 0xffffu) * K, sn, cs); a0 += w0*sn; a3 += w0*cs; \
        sincos_rev((float)(e.x >> 16)     * K, sn, cs); a1 += w0*sn; a4 += w0*cs; \
        sincos_rev((float)(e.y)           * K, sn, cs); a2 += w0*sn; a5 += w0*cs; \
        sincos_rev((float)(e.z & 0xffffu) * K, sn, cs); a0 += w1*sn; a3 += w1*cs; \
        sincos_rev((float)(e.z >> 16)     * K, sn, cs); a1 += w1*sn; a4 += w1*cs; \
        sincos_rev((float)(e.w)           * K, sn, cs); a2 += w1*sn; a5 += w1*cs; \
    }
    float a0 = 0.f, a1 = 0.f, a2 = 0.f, a3 = 0.f, a4 = 0.f, a5 = 0.f;
    {
        const float wz0 = 1.0f - ozA;
        const float wx0 = 1.0f - oxA, wy0 = 1.0f - oyA;
        PAIRE(eA0, wx0 * wy0, ozA, wz0, a0, a1, a2, a3, a4, a5)
        PAIRE(eA1, wx0 * oyA, ozA, wz0, a0, a1, a2, a3, a4, a5)
        PAIRE(eA2, oxA * wy0, ozA, wz0, a0, a1, a2, a3, a4, a5)
        PAIRE(eA3, oxA * oyA, ozA, wz0, a0, a1, a2, a3, a4, a5)
    }
    float b0 = 0.f, b1 = 0.f, b2 = 0.f, b3 = 0.f, b4 = 0.f, b5 = 0.f;
    {
        const float wz0 = 1.0f - ozB;
        const float wx0 = 1.0f - oxB, wy0 = 1.0f - oyB;
        PAIRE(eB0, wx0 * wy0, ozB, wz0, b0, b1, b2, b3, b4, b5)
        PAIRE(eB1, wx0 * oyB, ozB, wz0, b0, b1, b2, b3, b4, b5)
        PAIRE(eB2, oxB * wy0, ozB, wz0, b0, b1, b2, b3, b4, b5)
        PAIRE(eB3, oxB * oyB, ozB, wz0, b0, b1, b2, b3, b4, b5)
    }
    #undef PAIRE

    {
        const int c = 3 + l * 6;
        float* rowA = sres[p];
        rowA[c + 0] = a0; rowA[c + 1] = a1; rowA[c + 2] = a2;
        rowA[c + 3] = a3; rowA[c + 4] = a4; rowA[c + 5] = a5;
        float* rowB = sres[p + 32];
        rowB[c + 0] = b0; rowB[c + 1] = b1; rowB[c + 2] = b2;
        rowB[c + 3] = b3; rowB[c + 4] = b4; rowB[c + 5] = b5;
        if (l == 0) {
            rowA[0] = rxA; rowA[1] = ryA; rowA[2] = rzA;
            rowB[0] = rxB; rowB[1] = ryB; rowB[2] = rzB;
        }
    }
    __syncthreads();

    if (full_block) {
        const float4* flat4 = (const float4*)&sres[0][0];
        float4* ob4 = (float4*)(out + (size_t)block_base * ROW_F);
        for (int i = tid; i < (PTS_PER_BLOCK * ROW_F) / 4; i += 256)
            ob4[i] = flat4[i];
    } else {
        const float* flat = &sres[0][0];
        float* ob = out + (size_t)block_base * ROW_F;
        const int lim = npts * ROW_F - block_base * ROW_F;
        for (int i = tid; i < PTS_PER_BLOCK * ROW_F; i += 256)
            if (i < lim) ob[i] = flat[i];
    }
}

extern "C" void kernel_launch(void* const* d_in, const int* in_sizes, int n_in,
                              void* d_out, int out_size, void* d_ws, size_t ws_size,
                              hipStream_t stream) {
    const float* xyz           = (const float*)d_in[0];
    const float* data          = (const float*)d_in[1];
    const float* scales        = (const float*)d_in[2];
    const int*   level_offsets = (const int*)d_in[3];
    const float* bounds        = (const float*)d_in[4];
    float* out = (float*)d_out;

    const int npts = in_sizes[0] / 3;
    const int T    = in_sizes[1] / 3;
    const int N    = npts;

    // ws layout: [tab16 T*16][hist NCNT*4][offs NCNT*4][sidx N*4][sxyz N*12]
    const size_t off_tab  = 0;
    const size_t off_hist = (size_t)T * 16;
    const size_t off_offs = off_hist + (size_t)NCNT * 4;
    const size_t off_sidx = off_offs + (size_t)NCNT * 4;
    const size_t off_sxyz = off_sidx + (size_t)N * 4;
    const size_t need_full = off_sxyz + (size_t)N * 12;

    char* ws = (char*)d_ws;
    if (d_ws != nullptr && ws_size >= need_full) {
        uint4*    tab    = (uint4*)(ws + off_tab);
        unsigned* hist   = (unsigned*)(ws + off_hist);
        unsigned* offs   = (unsigned*)(ws + off_offs);
        int*      g_sidx = (int*)(ws + off_sidx);
        float*    g_sxyz = (float*)(ws + off_sxyz);

        hipMemsetAsync(hist, 0, (size_t)NCNT * 4, stream);
        const int rblocks = max((T + 255) / 256, (N + 255) / 256);
        repack_hist<<<rblocks, 256, 0, stream>>>(data, level_offsets, xyz, bounds,
                                                 tab, hist, T, N);
        sort_scan<<<1, 1024, 0, stream>>>(hist, offs);
        sort_scatter<<<(N + 255) / 256, 256, 0, stream>>>(xyz, bounds, offs,
                                                          g_sidx, g_sxyz, N);
        const int nwg = (N + PTS_PER_BLOCK - 1) / PTS_PER_BLOCK;
        dagrid_sorted<<<nwg, 256, 0, stream>>>(g_sxyz, g_sidx, tab, scales,
                                               level_offsets, bounds, out, N, nwg);
    } else if (d_ws != nullptr && ws_size >= (size_t)T * 8) {
        uint2* tab = (uint2*)d_ws;
        phase_repack8<<<(T + 255) / 256, 256, 0, stream>>>(data, level_offsets, tab, T);
        const int nblocks = (npts + PTS_PER_BLOCK - 1) / PTS_PER_BLOCK;
        dagrid_kernel8<<<nblocks, 256, 0, stream>>>(xyz, tab, scales, level_offsets,
                                                    bounds, out, npts);
    }
}

// Round 14
// 142.404 us; speedup vs baseline: 2.8249x; 2.8249x over previous
//
#include <hip/hip_runtime.h>

#define NLEV 8
#define PTS_PER_BLOCK 64
#define ROW_F 51   // 3 + 6*NLEV

typedef unsigned int u32x2 __attribute__((ext_vector_type(2)));

// ---------------------------------------------------------------------------
// Phase repack: data (T anchors x 3 f32) -> tab (T x 8B entries).
// Entry i = anchor i's 3 components as u16 phases (revolutions*65536),
// phase = fract(val * 2^l / 2pi), l = level owning anchor i.  (proven R6: ~13us)
// ---------------------------------------------------------------------------
__global__ __launch_bounds__(256) void phase_repack8(
    const float* __restrict__ data,
    const int*   __restrict__ level_offsets,
    uint2* __restrict__ tab, int T)
{
    __shared__ float sv[256 * 3];
    __shared__ int   soff[NLEV];
    const int tid  = threadIdx.x;
    const int base = blockIdx.x * 256;
    if (tid < NLEV) soff[tid] = level_offsets[tid];
    for (int k = tid; k < 256 * 3; k += 256) {
        const int gi = base * 3 + k;
        sv[k] = (gi < T * 3) ? data[gi] : 0.0f;
    }
    __syncthreads();
    const int i = base + tid;
    if (i >= T) return;
    int l = 0;
    #pragma unroll
    for (int j = 1; j < NLEV; ++j) l += (i >= soff[j]) ? 1 : 0;
    const float s = (float)(1 << l) * 0.15915494309189535f;   // freq / 2pi
    unsigned q[3];
    #pragma unroll
    for (int k = 0; k < 3; ++k) {
        float f = sv[tid * 3 + k] * s;
        f -= floorf(f);                             // [0,1) revolutions
        q[k] = ((unsigned)(f * 65536.0f + 0.5f)) & 0xffffu;  // 65536 wraps to 0
    }
    tab[i] = make_uint2(q[0] | (q[1] << 16), q[2]);
}

// sin/cos on revolutions in [0,1): pre-reduced domain for HW trans units
__device__ __forceinline__ void sincos_rev(float r, float& sn, float& cs) {
    asm("v_sin_f32 %0, %1" : "=v"(sn) : "v"(r));
    asm("v_cos_f32 %0, %1" : "=v"(cs) : "v"(r));
}

#define LOAD_BOUNDS                                                              \
    const float lox = bounds[0], loy = bounds[1], loz = bounds[2];               \
    const float hix = bounds[3] - 1e-6f;                                         \
    const float hiy = bounds[4] - 1e-6f;                                         \
    const float hiz = bounds[5] - 1e-6f;                                         \
    const float size = fmaxf(fmaxf(bounds[3] - bounds[0], bounds[4] - bounds[1]),\
                             bounds[5] - bounds[2]);                             \
    const float inv_size = 1.0f / size;

// ---------------------------------------------------------------------------
// Main kernel: 2 (point,level) units per thread; each corner-pair gathered as
// TWO aligned dwordx2 (never crossing a 16B segment) instead of one 8B-aligned
// dwordx4 (which crosses half the time, 4.15 vs 2.77 cyc — R8/R9 model).
// 16 hand-issued loads, ONE vmcnt drain (R8-verified batch pattern).
// ---------------------------------------------------------------------------
__global__ __launch_bounds__(256, 4) void dagrid_kernel8(
    const float* __restrict__ xyz,
    const uint2* __restrict__ tab,
    const float* __restrict__ scales,
    const int*   __restrict__ level_offsets,
    const float* __restrict__ bounds,
    float* __restrict__ out,
    int npts)
{
    __shared__ alignas(16) float sxyz[PTS_PER_BLOCK * 3];
    __shared__ alignas(16) float sres[PTS_PER_BLOCK][ROW_F];

    const int tid = threadIdx.x;
    const int l   = tid & 7;        // level (shared by both units)
    const int p   = tid >> 3;       // local point A: 0..31; point B: p+32
    const int block_base = blockIdx.x * PTS_PER_BLOCK;
    const bool full_block = (block_base + PTS_PER_BLOCK <= npts);

    if (full_block) {
        if (tid < 48)
            ((float4*)sxyz)[tid] = ((const float4*)(xyz + (size_t)block_base * 3))[tid];
    } else if (tid < PTS_PER_BLOCK * 3) {
        const int gi = block_base * 3 + tid;
        sxyz[tid] = (gi < npts * 3) ? xyz[gi] : 0.0f;
    }
    const float scale = scales[l];
    const int   off_l = level_offsets[l];
    LOAD_BOUNDS
    __syncthreads();

    const float rxA = sxyz[p * 3 + 0], ryA = sxyz[p * 3 + 1], rzA = sxyz[p * 3 + 2];
    const float rxB = sxyz[(p + 32) * 3 + 0], ryB = sxyz[(p + 32) * 3 + 1],
                rzB = sxyz[(p + 32) * 3 + 2];
    const int r1   = (int)scale + 1;
    const int r1sq = r1 * r1;
    const bool actA = (block_base + p) < npts;
    const bool actB = (block_base + p + 32) < npts;

    #define ADDR(rx, ry, rz, act, ox, oy, oz, idx)                                \
    {                                                                             \
        const float x = fminf(fmaxf(rx, lox), hix);                               \
        const float y = fminf(fmaxf(ry, loy), hiy);                               \
        const float z = fminf(fmaxf(rz, loz), hiz);                               \
        const float fx = (x - lox) * inv_size * scale;                            \
        const float fy = (y - loy) * inv_size * scale;                            \
        const float fz = (z - loz) * inv_size * scale;                            \
        const float bxf = floorf(fx), byf = floorf(fy), bzf = floorf(fz);         \
        ox = fx - bxf; oy = fy - byf; oz = fz - bzf;                              \
        idx = act ? ((int)bxf * r1sq + (int)byf * r1 + (int)bzf + off_l) : 0;     \
    }
    float oxA, oyA, ozA, oxB, oyB, ozB;
    int idxA, idxB;
    ADDR(rxA, ryA, rzA, actA, oxA, oyA, ozA, idxA)
    ADDR(rxB, ryB, rzB, actB, oxB, oyB, ozB, idxB)
    #undef ADDR

    // ---- gather: 8 corner-pairs x 2 aligned dwordx2 (offset:8 for the 2nd).
    const unsigned long long baseAddr = (unsigned long long)tab;
    const unsigned long long aA = baseAddr + 8ull * (unsigned)idxA;
    const unsigned long long aB = baseAddr + 8ull * (unsigned)idxB;
    const unsigned long long sY = 8ull * (unsigned)r1;     // +y corner step
    const unsigned long long sX = 8ull * (unsigned)r1sq;   // +x corner step

    u32x2 A0a, A0b, A1a, A1b, A2a, A2b, A3a, A3b;
    u32x2 B0a, B0b, B1a, B1b, B2a, B2b, B3a, B3b;
    #define GLOAD2(d0, d1, addr)                                                  \
        asm volatile("global_load_dwordx2 %0, %2, off\n\t"                        \
                     "global_load_dwordx2 %1, %2, off offset:8"                   \
                     : "=&v"(d0), "=&v"(d1) : "v"(addr))
    GLOAD2(A0a, A0b, aA);
    GLOAD2(A1a, A1b, aA + sY);
    GLOAD2(A2a, A2b, aA + sX);
    GLOAD2(A3a, A3b, aA + sX + sY);
    GLOAD2(B0a, B0b, aB);
    GLOAD2(B1a, B1b, aB + sY);
    GLOAD2(B2a, B2b, aB + sX);
    GLOAD2(B3a, B3b, aB + sX + sY);
    #undef GLOAD2
    // all 16 in flight; single drain; "+v" pins every consumer below the wait.
    asm volatile("s_waitcnt vmcnt(0)"
                 : "+v"(A0a), "+v"(A0b), "+v"(A1a), "+v"(A1b),
                   "+v"(A2a), "+v"(A2b), "+v"(A3a), "+v"(A3b),
                   "+v"(B0a), "+v"(B0b), "+v"(B1a), "+v"(B1b),
                   "+v"(B2a), "+v"(B2b), "+v"(B3a), "+v"(B3b));
    __builtin_amdgcn_sched_barrier(0);

    const float K = 1.0f / 65536.0f;   // u16 phase -> revolutions

    // ea = anchor(cx,cy,z): [q0|q1<<16, q2]; eb = anchor(cx,cy,z+1)
    #define PAIRE2(ea, eb, WXY, oz_, wz0_, a0, a1, a2, a3, a4, a5)                \
    {                                                                             \
        const float w0 = (WXY) * (wz0_);                                          \
        const float w1 = (WXY) * (oz_);                                           \
        float sn, cs;                                                             \
        sincos_rev((float)(ea.x & 0xffffu) * K, sn, cs); a0 += w0*sn; a3 += w0*cs;\
        sincos_rev((float)(ea.x >> 16)     * K, sn, cs); a1 += w0*sn; a4 += w0*cs;\
        sincos_rev((float)(ea.y)           * K, sn, cs); a2 += w0*sn; a5 += w0*cs;\
        sincos_rev((float)(eb.x & 0xffffu) * K, sn, cs); a0 += w1*sn; a3 += w1*cs;\
        sincos_rev((float)(eb.x >> 16)     * K, sn, cs); a1 += w1*sn; a4 += w1*cs;\
        sincos_rev((float)(eb.y)           * K, sn, cs); a2 += w1*sn; a5 += w1*cs;\
    }

    float a0 = 0.f, a1 = 0.f, a2 = 0.f, a3 = 0.f, a4 = 0.f, a5 = 0.f;
    {
        const float wz0 = 1.0f - ozA;
        const float wx0 = 1.0f - oxA, wy0 = 1.0f - oyA;
        PAIRE2(A0a, A0b, wx0 * wy0, ozA, wz0, a0, a1, a2, a3, a4, a5)
        PAIRE2(A1a, A1b, wx0 * oyA, ozA, wz0, a0, a1, a2, a3, a4, a5)
        PAIRE2(A2a, A2b, oxA * wy0, ozA, wz0, a0, a1, a2, a3, a4, a5)
        PAIRE2(A3a, A3b, oxA * oyA, ozA, wz0, a0, a1, a2, a3, a4, a5)
    }
    float b0 = 0.f, b1 = 0.f, b2 = 0.f, b3 = 0.f, b4 = 0.f, b5 = 0.f;
    {
        const float wz0 = 1.0f - ozB;
        const float wx0 = 1.0f - oxB, wy0 = 1.0f - oyB;
        PAIRE2(B0a, B0b, wx0 * wy0, ozB, wz0, b0, b1, b2, b3, b4, b5)
        PAIRE2(B1a, B1b, wx0 * oyB, ozB, wz0, b0, b1, b2, b3, b4, b5)
        PAIRE2(B2a, B2b, oxB * wy0, ozB, wz0, b0, b1, b2, b3, b4, b5)
        PAIRE2(B3a, B3b, oxB * oyB, ozB, wz0, b0, b1, b2, b3, b4, b5)
    }
    #undef PAIRE2

    {
        const int c = 3 + l * 6;
        float* rowA = sres[p];
        rowA[c + 0] = a0; rowA[c + 1] = a1; rowA[c + 2] = a2;
        rowA[c + 3] = a3; rowA[c + 4] = a4; rowA[c + 5] = a5;
        float* rowB = sres[p + 32];
        rowB[c + 0] = b0; rowB[c + 1] = b1; rowB[c + 2] = b2;
        rowB[c + 3] = b3; rowB[c + 4] = b4; rowB[c + 5] = b5;
        if (l == 0) {
            rowA[0] = rxA; rowA[1] = ryA; rowA[2] = rzA;
            rowB[0] = rxB; rowB[1] = ryB; rowB[2] = rzB;
        }
    }
    __syncthreads();

    // coalesced write: 64*51 = 3264 floats = 816 float4 per block (16B aligned)
    if (full_block) {
        const float4* flat4 = (const float4*)&sres[0][0];
        float4* ob4 = (float4*)(out + (size_t)block_base * ROW_F);
        for (int i = tid; i < (PTS_PER_BLOCK * ROW_F) / 4; i += 256)
            ob4[i] = flat4[i];
    } else {
        const float* flat = &sres[0][0];
        float* ob = out + (size_t)block_base * ROW_F;
        const int lim = npts * ROW_F - block_base * ROW_F;
        for (int i = tid; i < PTS_PER_BLOCK * ROW_F; i += 256)
            if (i < lim) ob[i] = flat[i];
    }
}

// ---------------------------------------------------------------------------
// Fallback (ws too small): direct fp32 gather (x4u + x2u), known-good (R3).
// ---------------------------------------------------------------------------
typedef float f4u __attribute__((ext_vector_type(4), aligned(4)));
typedef float f2u __attribute__((ext_vector_type(2), aligned(4)));

__global__ __launch_bounds__(256) void dagrid_kernel_direct(
    const float* __restrict__ xyz,
    const float* __restrict__ data,
    const float* __restrict__ scales,
    const int*   __restrict__ level_offsets,
    const float* __restrict__ bounds,
    float* __restrict__ out,
    int npts)
{
    __shared__ alignas(16) float sxyz[32 * 3];
    __shared__ alignas(16) float sres[32][ROW_F];

    const int tid = threadIdx.x;
    const int l   = tid & 7;
    const int p   = tid >> 3;
    const int block_base = blockIdx.x * 32;

    if (tid < 32 * 3) {
        const int gi = block_base * 3 + tid;
        sxyz[tid] = (gi < npts * 3) ? xyz[gi] : 0.0f;
    }
    const float scale = scales[l];
    const int   off_l = level_offsets[l];
    LOAD_BOUNDS
    __syncthreads();

    const int n = block_base + p;
    const bool active = (n < npts);
    const float rx = sxyz[p * 3 + 0];
    const float ry = sxyz[p * 3 + 1];
    const float rz = sxyz[p * 3 + 2];
    float acc0 = 0.f, acc1 = 0.f, acc2 = 0.f, acc3 = 0.f, acc4 = 0.f, acc5 = 0.f;

    if (active) {
        const float x = fminf(fmaxf(rx, lox), hix);
        const float y = fminf(fmaxf(ry, loy), hiy);
        const float z = fminf(fmaxf(rz, loz), hiz);
        const float xn = (x - lox) * inv_size;
        const float yn = (y - loy) * inv_size;
        const float zn = (z - loz) * inv_size;
        const int r1 = (int)scale + 1;
        const int r1sq = r1 * r1;
        const float fx = xn * scale, fy = yn * scale, fz = zn * scale;
        const float bxf = floorf(fx), byf = floorf(fy), bzf = floorf(fz);
        const float ox = fx - bxf, oy = fy - byf, oz = fz - bzf;
        const int i000 = (int)bxf * r1sq + (int)byf * r1 + (int)bzf + off_l;
        const float* p0 = data + 3 * (size_t)i000;
        const float* p1 = p0 + 3 * r1;
        const float* p2 = p0 + 3 * r1sq;
        const float* p3 = p2 + 3 * r1;
        const f4u q0 = *(const f4u*)p0;  const f2u g0 = *(const f2u*)(p0 + 4);
        const f4u q1 = *(const f4u*)p1;  const f2u g1 = *(const f2u*)(p1 + 4);
        const f4u q2 = *(const f4u*)p2;  const f2u g2 = *(const f2u*)(p2 + 4);
        const f4u q3 = *(const f4u*)p3;  const f2u g3 = *(const f2u*)(p3 + 4);
        const float freq = (float)(1 << l);
        const float wz0 = 1.0f - oz;
        const float wx1 = ox, wx0 = 1.0f - ox;
        const float wy1 = oy, wy0 = 1.0f - oy;
        float sn, cs;
        #define PAIR(a, b, WXY)                                                   \
        {                                                                         \
            const float w0 = (WXY) * wz0;                                         \
            const float w1 = (WXY) * oz;                                          \
            __sincosf(a.x * freq, &sn, &cs); acc0 += w0 * sn; acc3 += w0 * cs;    \
            __sincosf(a.y * freq, &sn, &cs); acc1 += w0 * sn; acc4 += w0 * cs;    \
            __sincosf(a.z * freq, &sn, &cs); acc2 += w0 * sn; acc5 += w0 * cs;    \
            __sincosf(a.w * freq, &sn, &cs); acc0 += w1 * sn; acc3 += w1 * cs;    \
            __sincosf(b.x * freq, &sn, &cs); acc1 += w1 * sn; acc4 += w1 * cs;    \
            __sincosf(b.y * freq, &sn, &cs); acc2 += w1 * sn; acc5 += w1 * cs;    \
        }
        PAIR(q0, g0, wx0 * wy0)
        PAIR(q1, g1, wx0 * wy1)
        PAIR(q2, g2, wx1 * wy0)
        PAIR(q3, g3, wx1 * wy1)
        #undef PAIR
    }
    {
        float* row = sres[p];
        const int c = 3 + l * 6;
        row[c + 0] = acc0; row[c + 1] = acc1; row[c + 2] = acc2;
        row[c + 3] = acc3; row[c + 4] = acc4; row[c + 5] = acc5;
        if (l == 0) { row[0] = rx; row[1] = ry; row[2] = rz; }
    }
    __syncthreads();
    {
        const float* flat = &sres[0][0];
        float* ob = out + (size_t)block_base * ROW_F;
        const int lim = npts * ROW_F - block_base * ROW_F;
        for (int i = tid; i < 32 * ROW_F; i += 256)
            if (i < lim) ob[i] = flat[i];
    }
}

extern "C" void kernel_launch(void* const* d_in, const int* in_sizes, int n_in,
                              void* d_out, int out_size, void* d_ws, size_t ws_size,
                              hipStream_t stream) {
    const float* xyz           = (const float*)d_in[0];
    const float* data          = (const float*)d_in[1];
    const float* scales        = (const float*)d_in[2];
    const int*   level_offsets = (const int*)d_in[3];
    const float* bounds        = (const float*)d_in[4];
    float* out = (float*)d_out;

    const int npts = in_sizes[0] / 3;
    const int T    = in_sizes[1] / 3;

    if (d_ws != nullptr && ws_size >= (size_t)T * 8) {
        uint2* tab = (uint2*)d_ws;
        phase_repack8<<<(T + 255) / 256, 256, 0, stream>>>(data, level_offsets, tab, T);
        const int nblocks = (npts + PTS_PER_BLOCK - 1) / PTS_PER_BLOCK;
        dagrid_kernel8<<<nblocks, 256, 0, stream>>>(xyz, tab, scales, level_offsets,
                                                    bounds, out, npts);
    } else {
        const int nblocks = (npts + 31) / 32;
        dagrid_kernel_direct<<<nblocks, 256, 0, stream>>>(xyz, data, scales,
                                                          level_offsets, bounds,
                                                          out, npts);
    }
}